// Round 1
// baseline (537.721 us; speedup 1.0000x reference)
//
#include <hip/hip_runtime.h>

#define N_NODES 50000
#define N_EDGES 800000
#define FEAT 128
#define N_GRAPHS 512

// ---------------------------------------------------------------------------
// 1) count in-degree (real edges only; self-loop handled analytically)
// ---------------------------------------------------------------------------
__global__ __launch_bounds__(256) void count_kernel(const int* __restrict__ dst,
                                                    int* __restrict__ cnt) {
    int e = blockIdx.x * 256 + threadIdx.x;
    if (e < N_EDGES) atomicAdd(&cnt[dst[e]], 1);
}

// ---------------------------------------------------------------------------
// 2) single-block exclusive scan of cnt -> rowptr; also dinv = rsqrt(cnt+1)
// ---------------------------------------------------------------------------
__global__ __launch_bounds__(1024) void scan_kernel(const int* __restrict__ cnt,
                                                    int* __restrict__ rowptr,
                                                    float* __restrict__ dinv) {
    __shared__ int sums[1024];
    const int n = N_NODES;
    int tid = threadIdx.x;
    const int chunk = (n + 1023) / 1024;  // 49
    int begin = tid * chunk;
    int end = min(begin + chunk, n);
    int s = 0;
    for (int i = begin; i < end; ++i) s += cnt[i];
    sums[tid] = s;
    __syncthreads();
    for (int off = 1; off < 1024; off <<= 1) {
        int t = (tid >= off) ? sums[tid - off] : 0;
        __syncthreads();
        sums[tid] += t;
        __syncthreads();
    }
    int run = sums[tid] - s;  // exclusive prefix of this chunk
    for (int i = begin; i < end; ++i) {
        rowptr[i] = run;
        run += cnt[i];
        dinv[i] = rsqrtf((float)(cnt[i] + 1));  // +1 self-loop
    }
    if (tid == 1023) rowptr[n] = run;  // == N_EDGES
}

// ---------------------------------------------------------------------------
// 3) scatter edges into CSR buckets
// ---------------------------------------------------------------------------
__global__ __launch_bounds__(256) void scatter_kernel(const int* __restrict__ src,
                                                      const int* __restrict__ dst,
                                                      const int* __restrict__ rowptr,
                                                      int* __restrict__ woff,
                                                      int* __restrict__ csr_src) {
    int e = blockIdx.x * 256 + threadIdx.x;
    if (e >= N_EDGES) return;
    int d = dst[e];
    int pos = atomicAdd(&woff[d], 1);
    csr_src[rowptr[d] + pos] = src[e];
}

// ---------------------------------------------------------------------------
// 4) fp32 GEMM  H[M,128] = X[M,128] @ W[128,128]   (no bias here)
//    block: 256 thr, 64-row tile, per-thread 4 rows x 8 cols register block
// ---------------------------------------------------------------------------
__global__ __launch_bounds__(256) void gemm_kernel(const float* __restrict__ X,
                                                   const float* __restrict__ W,
                                                   float* __restrict__ H, int M) {
    __shared__ float sX[64][132];  // +4 pad: 2-way max conflict on reads
    __shared__ float sW[64][132];
    int tid = threadIdx.x;
    int row0 = blockIdx.x * 64;

    // stage X tile (64 x 128), coalesced float4
#pragma unroll
    for (int it = 0; it < 8; ++it) {
        int idx = tid + it * 256;         // 2048 float4 slots
        int r = idx >> 5, q = idx & 31;
        int grow = row0 + r;
        float4 v = make_float4(0.f, 0.f, 0.f, 0.f);
        if (grow < M) v = *reinterpret_cast<const float4*>(X + grow * 128 + q * 4);
        *reinterpret_cast<float4*>(&sX[r][q * 4]) = v;
    }

    int tx = tid & 15;  // cols tx*4..+3 and 64+tx*4..+3
    int ty = tid >> 4;  // rows ty*4..+3
    float acc[4][8];
#pragma unroll
    for (int i = 0; i < 4; ++i)
#pragma unroll
        for (int j = 0; j < 8; ++j) acc[i][j] = 0.f;

    for (int k0 = 0; k0 < 128; k0 += 64) {
        __syncthreads();  // protects sX (first iter) and sW (reuse)
#pragma unroll
        for (int it = 0; it < 8; ++it) {
            int idx = tid + it * 256;
            int r = idx >> 5, q = idx & 31;
            *reinterpret_cast<float4*>(&sW[r][q * 4]) =
                *reinterpret_cast<const float4*>(W + (k0 + r) * 128 + q * 4);
        }
        __syncthreads();
#pragma unroll 16
        for (int k = 0; k < 64; ++k) {
            float xv[4];
#pragma unroll
            for (int ri = 0; ri < 4; ++ri) xv[ri] = sX[ty * 4 + ri][k0 + k];
            float4 w0 = *reinterpret_cast<const float4*>(&sW[k][tx * 4]);
            float4 w1 = *reinterpret_cast<const float4*>(&sW[k][64 + tx * 4]);
            float wv[8] = {w0.x, w0.y, w0.z, w0.w, w1.x, w1.y, w1.z, w1.w};
#pragma unroll
            for (int ri = 0; ri < 4; ++ri)
#pragma unroll
                for (int ci = 0; ci < 8; ++ci) acc[ri][ci] += xv[ri] * wv[ci];
        }
    }
#pragma unroll
    for (int ri = 0; ri < 4; ++ri) {
        int grow = row0 + ty * 4 + ri;
        if (grow >= M) continue;
        float4 o0 = make_float4(acc[ri][0], acc[ri][1], acc[ri][2], acc[ri][3]);
        float4 o1 = make_float4(acc[ri][4], acc[ri][5], acc[ri][6], acc[ri][7]);
        *reinterpret_cast<float4*>(H + grow * 128 + tx * 4) = o0;
        *reinterpret_cast<float4*>(H + grow * 128 + 64 + tx * 4) = o1;
    }
}

// ---------------------------------------------------------------------------
// 5) aggregation: out[i] = relu( dinv[i]*( sum_e dinv[s]*Hpre[s] + dinv[i]*Hpre[i] ) + b )
//    one wave per node, lane l holds features {2l, 2l+1} (float2)
// ---------------------------------------------------------------------------
__global__ __launch_bounds__(256) void aggregate_kernel(const float* __restrict__ Hpre,
                                                        const float* __restrict__ dinv,
                                                        const int* __restrict__ rowptr,
                                                        const int* __restrict__ csr_src,
                                                        const float* __restrict__ bias,
                                                        float* __restrict__ Hout, int n) {
    int node = blockIdx.x * 4 + (threadIdx.x >> 6);
    if (node >= n) return;
    int lane = threadIdx.x & 63;
    int start = rowptr[node], end = rowptr[node + 1];
    float ax = 0.f, ay = 0.f;
    for (int e = start; e < end; ++e) {
        int s = csr_src[e];              // wave-uniform -> broadcast load
        float w = dinv[s];
        float2 hv = *reinterpret_cast<const float2*>(Hpre + s * 128 + lane * 2);
        ax += w * hv.x;
        ay += w * hv.y;
    }
    float di = dinv[node];
    float2 hs = *reinterpret_cast<const float2*>(Hpre + node * 128 + lane * 2);
    float bx = bias[lane * 2], by = bias[lane * 2 + 1];
    float ox = fmaxf(di * (ax + di * hs.x) + bx, 0.f);
    float oy = fmaxf(di * (ay + di * hs.y) + by, 0.f);
    *reinterpret_cast<float2*>(Hout + node * 128 + lane * 2) = make_float2(ox, oy);
}

// ---------------------------------------------------------------------------
// 6) readout: batch is SORTED -> per-graph contiguous node range via binary search
//    block = 256 (2 half-waves over nodes), thread f = feature
// ---------------------------------------------------------------------------
__global__ __launch_bounds__(256) void readout_kernel(const float* __restrict__ H,
                                                      const int* __restrict__ batch,
                                                      float* __restrict__ out) {
    int g = blockIdx.x;
    int f = threadIdx.x & 127;
    int half = threadIdx.x >> 7;
    const int n = N_NODES;
    // lower_bound(batch, key)
    auto lb = [&](int key) {
        int lo = 0, hi = n;
        while (lo < hi) {
            int mid = (lo + hi) >> 1;
            if (batch[mid] < key) lo = mid + 1; else hi = mid;
        }
        return lo;
    };
    int start = lb(g), end = lb(g + 1);
    float sum = 0.f, mx = 0.f;  // post-relu values >= 0; empty graph -> 0
    for (int i = start + half; i < end; i += 2) {
        float v = H[i * 128 + f];
        sum += v;
        mx = fmaxf(mx, v);
    }
    __shared__ float ssum[256], smax[256];
    ssum[threadIdx.x] = sum;
    smax[threadIdx.x] = mx;
    __syncthreads();
    if (half == 0) {
        sum += ssum[threadIdx.x + 128];
        mx = fmaxf(mx, smax[threadIdx.x + 128]);
        int cntg = end - start;
        float mean = sum / fmaxf((float)cntg, 1.0f);
        out[g * 384 + f] = sum;
        out[g * 384 + 128 + f] = mx;
        out[g * 384 + 256 + f] = mean;
    }
}

// ---------------------------------------------------------------------------
extern "C" void kernel_launch(void* const* d_in, const int* in_sizes, int n_in,
                              void* d_out, int out_size, void* d_ws, size_t ws_size,
                              hipStream_t stream) {
    const float* x = (const float*)d_in[0];
    const float* W1 = (const float*)d_in[1];
    const float* b1 = (const float*)d_in[2];
    const float* W2 = (const float*)d_in[3];
    const float* b2 = (const float*)d_in[4];
    const int* ei = (const int*)d_in[5];
    const int* batch = (const int*)d_in[6];
    const int* esrc = ei;             // edge_index[0]
    const int* edst = ei + N_EDGES;   // edge_index[1]
    float* out = (float*)d_out;

    char* ws = (char*)d_ws;
    // byte offsets (256B aligned)
    int* cnt      = (int*)(ws + 0);               // 200000 B
    int* woff     = (int*)(ws + 200704);          // 200000 B
    int* rowptr   = (int*)(ws + 401408);          // 200004 B
    float* dinv   = (float*)(ws + 602112);        // 200000 B
    int* csr_src  = (int*)(ws + 802816);          // 3.2 MB
    float* bufA   = (float*)(ws + 4002816);       // 25.6 MB
    float* bufB   = (float*)(ws + 29602816);      // 25.6 MB (ends ~52.7 MiB)

    hipMemsetAsync(cnt, 0, N_NODES * sizeof(int), stream);
    hipMemsetAsync(woff, 0, N_NODES * sizeof(int), stream);

    count_kernel<<<N_EDGES / 256, 256, 0, stream>>>(edst, cnt);
    scan_kernel<<<1, 1024, 0, stream>>>(cnt, rowptr, dinv);
    scatter_kernel<<<N_EDGES / 256, 256, 0, stream>>>(esrc, edst, rowptr, woff, csr_src);

    int gemm_blocks = (N_NODES + 63) / 64;
    // layer 1
    gemm_kernel<<<gemm_blocks, 256, 0, stream>>>(x, W1, bufA, N_NODES);
    aggregate_kernel<<<N_NODES / 4, 256, 0, stream>>>(bufA, dinv, rowptr, csr_src, b1, bufB, N_NODES);
    // layer 2
    gemm_kernel<<<gemm_blocks, 256, 0, stream>>>(bufB, W2, bufA, N_NODES);
    aggregate_kernel<<<N_NODES / 4, 256, 0, stream>>>(bufA, dinv, rowptr, csr_src, b2, bufB, N_NODES);
    // readout
    readout_kernel<<<N_GRAPHS, 256, 0, stream>>>(bufB, batch, out);
}

// Round 7
// 395.183 us; speedup vs baseline: 1.3607x; 1.3607x over previous
//
#include <hip/hip_runtime.h>

#define N_NODES 50000
#define N_EDGES 800000
#define FEAT 128
#define N_GRAPHS 512

#define SCAN_BLK 256
#define N_SCAN_BLOCKS ((N_NODES + SCAN_BLK - 1) / SCAN_BLK)  // 196

// ---------------------------------------------------------------------------
// 1) count in-degree (real edges only; self-loop handled analytically)
// ---------------------------------------------------------------------------
__global__ __launch_bounds__(256) void count_kernel(const int* __restrict__ dst,
                                                    int* __restrict__ cnt) {
    int e = blockIdx.x * 256 + threadIdx.x;
    if (e < N_EDGES) atomicAdd(&cnt[dst[e]], 1);
}

// ---------------------------------------------------------------------------
// 2a) per-block partial sums of cnt
// ---------------------------------------------------------------------------
__global__ __launch_bounds__(SCAN_BLK) void scan_partial_kernel(const int* __restrict__ cnt,
                                                                int* __restrict__ partial) {
    __shared__ int s[SCAN_BLK];
    int i = blockIdx.x * SCAN_BLK + threadIdx.x;
    s[threadIdx.x] = (i < N_NODES) ? cnt[i] : 0;
    __syncthreads();
#pragma unroll
    for (int off = SCAN_BLK / 2; off > 0; off >>= 1) {
        if (threadIdx.x < off) s[threadIdx.x] += s[threadIdx.x + off];
        __syncthreads();
    }
    if (threadIdx.x == 0) partial[blockIdx.x] = s[0];
}

// ---------------------------------------------------------------------------
// 2b) single block: exclusive scan of the 196 partials -> blockBase
// ---------------------------------------------------------------------------
__global__ __launch_bounds__(SCAN_BLK) void scan_base_kernel(const int* __restrict__ partial,
                                                             int* __restrict__ blockBase,
                                                             int* __restrict__ rowptr) {
    __shared__ int s[SCAN_BLK];
    int t = threadIdx.x;
    int v = (t < N_SCAN_BLOCKS) ? partial[t] : 0;
    s[t] = v;
    __syncthreads();
#pragma unroll
    for (int off = 1; off < SCAN_BLK; off <<= 1) {
        int u = (t >= off) ? s[t - off] : 0;
        __syncthreads();
        s[t] += u;
        __syncthreads();
    }
    if (t < N_SCAN_BLOCKS) blockBase[t] = s[t] - v;  // exclusive
    if (t == 0) rowptr[N_NODES] = N_EDGES;           // all dsts are in range
}

// ---------------------------------------------------------------------------
// 2c) per-block exclusive scan + base -> rowptr; also dinv = rsqrt(cnt+1)
// ---------------------------------------------------------------------------
__global__ __launch_bounds__(SCAN_BLK) void scan_apply_kernel(const int* __restrict__ cnt,
                                                              const int* __restrict__ blockBase,
                                                              int* __restrict__ rowptr,
                                                              float* __restrict__ dinv) {
    __shared__ int s[SCAN_BLK];
    int i = blockIdx.x * SCAN_BLK + threadIdx.x;
    int t = threadIdx.x;
    int v = (i < N_NODES) ? cnt[i] : 0;
    s[t] = v;
    __syncthreads();
#pragma unroll
    for (int off = 1; off < SCAN_BLK; off <<= 1) {
        int u = (t >= off) ? s[t - off] : 0;
        __syncthreads();
        s[t] += u;
        __syncthreads();
    }
    if (i < N_NODES) {
        rowptr[i] = blockBase[blockIdx.x] + s[t] - v;  // exclusive
        dinv[i] = rsqrtf((float)(v + 1));              // +1 self-loop
    }
}

// ---------------------------------------------------------------------------
// 3) scatter edges into CSR buckets
// ---------------------------------------------------------------------------
__global__ __launch_bounds__(256) void scatter_kernel(const int* __restrict__ src,
                                                      const int* __restrict__ dst,
                                                      const int* __restrict__ rowptr,
                                                      int* __restrict__ woff,
                                                      int* __restrict__ csr_src) {
    int e = blockIdx.x * 256 + threadIdx.x;
    if (e >= N_EDGES) return;
    int d = dst[e];
    int pos = atomicAdd(&woff[d], 1);
    csr_src[rowptr[d] + pos] = src[e];
}

// ---------------------------------------------------------------------------
// 4) fp32 GEMM  G[M,128] = dinv[row] * (X[M,128] @ W[128,128])
//    dinv scale folded into the epilogue ("pre-scaled messages")
// ---------------------------------------------------------------------------
__global__ __launch_bounds__(256) void gemm_kernel(const float* __restrict__ X,
                                                   const float* __restrict__ W,
                                                   const float* __restrict__ dinv,
                                                   float* __restrict__ G, int M) {
    __shared__ float sX[64][132];
    __shared__ float sW[64][132];
    int tid = threadIdx.x;
    int row0 = blockIdx.x * 64;

#pragma unroll
    for (int it = 0; it < 8; ++it) {
        int idx = tid + it * 256;
        int r = idx >> 5, q = idx & 31;
        int grow = row0 + r;
        float4 v = make_float4(0.f, 0.f, 0.f, 0.f);
        if (grow < M) v = *reinterpret_cast<const float4*>(X + grow * 128 + q * 4);
        *reinterpret_cast<float4*>(&sX[r][q * 4]) = v;
    }

    int tx = tid & 15;
    int ty = tid >> 4;
    float acc[4][8];
#pragma unroll
    for (int i = 0; i < 4; ++i)
#pragma unroll
        for (int j = 0; j < 8; ++j) acc[i][j] = 0.f;

    for (int k0 = 0; k0 < 128; k0 += 64) {
        __syncthreads();
#pragma unroll
        for (int it = 0; it < 8; ++it) {
            int idx = tid + it * 256;
            int r = idx >> 5, q = idx & 31;
            *reinterpret_cast<float4*>(&sW[r][q * 4]) =
                *reinterpret_cast<const float4*>(W + (k0 + r) * 128 + q * 4);
        }
        __syncthreads();
#pragma unroll 16
        for (int k = 0; k < 64; ++k) {
            float xv[4];
#pragma unroll
            for (int ri = 0; ri < 4; ++ri) xv[ri] = sX[ty * 4 + ri][k0 + k];
            float4 w0 = *reinterpret_cast<const float4*>(&sW[k][tx * 4]);
            float4 w1 = *reinterpret_cast<const float4*>(&sW[k][64 + tx * 4]);
            float wv[8] = {w0.x, w0.y, w0.z, w0.w, w1.x, w1.y, w1.z, w1.w};
#pragma unroll
            for (int ri = 0; ri < 4; ++ri)
#pragma unroll
                for (int ci = 0; ci < 8; ++ci) acc[ri][ci] += xv[ri] * wv[ci];
        }
    }
#pragma unroll
    for (int ri = 0; ri < 4; ++ri) {
        int grow = row0 + ty * 4 + ri;
        if (grow >= M) continue;
        float sc = dinv[grow];
        float4 o0 = make_float4(sc * acc[ri][0], sc * acc[ri][1], sc * acc[ri][2], sc * acc[ri][3]);
        float4 o1 = make_float4(sc * acc[ri][4], sc * acc[ri][5], sc * acc[ri][6], sc * acc[ri][7]);
        *reinterpret_cast<float4*>(G + grow * 128 + tx * 4) = o0;
        *reinterpret_cast<float4*>(G + grow * 128 + 64 + tx * 4) = o1;
    }
}

// ---------------------------------------------------------------------------
// 5) aggregation on pre-scaled messages:
//    out[i] = relu( dinv[i] * ( sum_{s in N(i)} G[s] + G[i] ) + b )
//    one wave per node; cooperative edge staging (64 ids loaded in parallel,
//    broadcast via shfl) -> gather loop has only independent loads + adds.
// ---------------------------------------------------------------------------
__global__ __launch_bounds__(256) void aggregate_kernel(const float* __restrict__ G,
                                                        const float* __restrict__ dinv,
                                                        const int* __restrict__ rowptr,
                                                        const int* __restrict__ csr_src,
                                                        const float* __restrict__ bias,
                                                        float* __restrict__ Hout, int n) {
    int node = blockIdx.x * 4 + (threadIdx.x >> 6);
    if (node >= n) return;
    int lane = threadIdx.x & 63;
    int start = rowptr[node], end = rowptr[node + 1];

    float di = dinv[node];
    float2 gs = *reinterpret_cast<const float2*>(G + node * 128 + lane * 2);  // self loop
    float bx = bias[lane * 2], by = bias[lane * 2 + 1];

    float ax = gs.x, ay = gs.y;
    for (int base = start; base < end; base += 64) {
        int idx = base + lane;
        int s_l = (idx < end) ? csr_src[idx] : 0;
        int nn = min(64, end - base);
#pragma unroll 4
        for (int j = 0; j < nn; ++j) {
            int s = __shfl(s_l, j);
            float2 hv = *reinterpret_cast<const float2*>(G + s * 128 + lane * 2);
            ax += hv.x;
            ay += hv.y;
        }
    }
    float ox = fmaxf(di * ax + bx, 0.f);
    float oy = fmaxf(di * ay + by, 0.f);
    *reinterpret_cast<float2*>(Hout + node * 128 + lane * 2) = make_float2(ox, oy);
}

// ---------------------------------------------------------------------------
// 6) readout: batch is SORTED -> per-graph contiguous node range via binary search
// ---------------------------------------------------------------------------
__global__ __launch_bounds__(256) void readout_kernel(const float* __restrict__ H,
                                                      const int* __restrict__ batch,
                                                      float* __restrict__ out) {
    int g = blockIdx.x;
    int f = threadIdx.x & 127;
    int half = threadIdx.x >> 7;
    const int n = N_NODES;
    auto lb = [&](int key) {
        int lo = 0, hi = n;
        while (lo < hi) {
            int mid = (lo + hi) >> 1;
            if (batch[mid] < key) lo = mid + 1; else hi = mid;
        }
        return lo;
    };
    int start = lb(g), end = lb(g + 1);
    float sum = 0.f, mx = 0.f;  // post-relu values >= 0; empty graph -> 0
    for (int i = start + half; i < end; i += 2) {
        float v = H[i * 128 + f];
        sum += v;
        mx = fmaxf(mx, v);
    }
    __shared__ float ssum[256], smax[256];
    ssum[threadIdx.x] = sum;
    smax[threadIdx.x] = mx;
    __syncthreads();
    if (half == 0) {
        sum += ssum[threadIdx.x + 128];
        mx = fmaxf(mx, smax[threadIdx.x + 128]);
        int cntg = end - start;
        float mean = sum / fmaxf((float)cntg, 1.0f);
        out[g * 384 + f] = sum;
        out[g * 384 + 128 + f] = mx;
        out[g * 384 + 256 + f] = mean;
    }
}

// ---------------------------------------------------------------------------
extern "C" void kernel_launch(void* const* d_in, const int* in_sizes, int n_in,
                              void* d_out, int out_size, void* d_ws, size_t ws_size,
                              hipStream_t stream) {
    const float* x = (const float*)d_in[0];
    const float* W1 = (const float*)d_in[1];
    const float* b1 = (const float*)d_in[2];
    const float* W2 = (const float*)d_in[3];
    const float* b2 = (const float*)d_in[4];
    const int* ei = (const int*)d_in[5];
    const int* batch = (const int*)d_in[6];
    const int* esrc = ei;             // edge_index[0]
    const int* edst = ei + N_EDGES;   // edge_index[1]
    float* out = (float*)d_out;

    char* ws = (char*)d_ws;
    int* cnt       = (int*)(ws + 0);               // 200000 B
    int* woff      = (int*)(ws + 200704);          // 200000 B
    int* rowptr    = (int*)(ws + 401408);          // 200004 B
    float* dinv    = (float*)(ws + 602112);        // 200000 B
    int* partial   = (int*)(ws + 802816);          // 784 B
    int* blockBase = (int*)(ws + 803840);          // 784 B
    int* csr_src   = (int*)(ws + 804864);          // 3.2 MB
    float* bufA    = (float*)(ws + 4004864);       // 25.6 MB
    float* bufB    = (float*)(ws + 29604864);      // 25.6 MB (ends ~52.7 MiB)

    hipMemsetAsync(cnt, 0, N_NODES * sizeof(int), stream);
    hipMemsetAsync(woff, 0, N_NODES * sizeof(int), stream);

    count_kernel<<<N_EDGES / 256, 256, 0, stream>>>(edst, cnt);
    scan_partial_kernel<<<N_SCAN_BLOCKS, SCAN_BLK, 0, stream>>>(cnt, partial);
    scan_base_kernel<<<1, SCAN_BLK, 0, stream>>>(partial, blockBase, rowptr);
    scan_apply_kernel<<<N_SCAN_BLOCKS, SCAN_BLK, 0, stream>>>(cnt, blockBase, rowptr, dinv);
    scatter_kernel<<<N_EDGES / 256, 256, 0, stream>>>(esrc, edst, rowptr, woff, csr_src);

    int gemm_blocks = (N_NODES + 63) / 64;
    // layer 1: G1 = dinv .* (x@W1) ; H1 = relu(dinv .* (A_csr G1) + b1)
    gemm_kernel<<<gemm_blocks, 256, 0, stream>>>(x, W1, dinv, bufA, N_NODES);
    aggregate_kernel<<<N_NODES / 4, 256, 0, stream>>>(bufA, dinv, rowptr, csr_src, b1, bufB, N_NODES);
    // layer 2
    gemm_kernel<<<gemm_blocks, 256, 0, stream>>>(bufB, W2, dinv, bufA, N_NODES);
    aggregate_kernel<<<N_NODES / 4, 256, 0, stream>>>(bufA, dinv, rowptr, csr_src, b2, bufB, N_NODES);
    // readout
    readout_kernel<<<N_GRAPHS, 256, 0, stream>>>(bufB, batch, out);
}

// Round 9
// 373.571 us; speedup vs baseline: 1.4394x; 1.0579x over previous
//
#include <hip/hip_runtime.h>

#define N_NODES 50000
#define N_EDGES 800000
#define FEAT 128
#define N_GRAPHS 512

#define SCAN_BLK 256
#define N_SCAN_BLOCKS ((N_NODES + SCAN_BLK - 1) / SCAN_BLK)  // 196

// float -> bf16 bits, round-to-nearest-even
__device__ __forceinline__ unsigned int f2bf(float f) {
    unsigned int u = __float_as_uint(f);
    return (u + 0x7fffu + ((u >> 16) & 1u)) >> 16;
}
// bf16 pair (packed in uint) -> two floats
__device__ __forceinline__ float bf_lo(unsigned int u) { return __uint_as_float(u << 16); }
__device__ __forceinline__ float bf_hi(unsigned int u) { return __uint_as_float(u & 0xffff0000u); }

// ---------------------------------------------------------------------------
// 1) count in-degree (real edges only; self-loop handled analytically)
// ---------------------------------------------------------------------------
__global__ __launch_bounds__(256) void count_kernel(const int* __restrict__ dst,
                                                    int* __restrict__ cnt) {
    int e = blockIdx.x * 256 + threadIdx.x;
    if (e < N_EDGES) atomicAdd(&cnt[dst[e]], 1);
}

// ---------------------------------------------------------------------------
// 2a) per-block partial sums of cnt
// ---------------------------------------------------------------------------
__global__ __launch_bounds__(SCAN_BLK) void scan_partial_kernel(const int* __restrict__ cnt,
                                                                int* __restrict__ partial) {
    __shared__ int s[SCAN_BLK];
    int i = blockIdx.x * SCAN_BLK + threadIdx.x;
    s[threadIdx.x] = (i < N_NODES) ? cnt[i] : 0;
    __syncthreads();
#pragma unroll
    for (int off = SCAN_BLK / 2; off > 0; off >>= 1) {
        if (threadIdx.x < off) s[threadIdx.x] += s[threadIdx.x + off];
        __syncthreads();
    }
    if (threadIdx.x == 0) partial[blockIdx.x] = s[0];
}

// ---------------------------------------------------------------------------
// 2b) single block: exclusive scan of the 196 partials -> blockBase
// ---------------------------------------------------------------------------
__global__ __launch_bounds__(SCAN_BLK) void scan_base_kernel(const int* __restrict__ partial,
                                                             int* __restrict__ blockBase,
                                                             int* __restrict__ rowptr) {
    __shared__ int s[SCAN_BLK];
    int t = threadIdx.x;
    int v = (t < N_SCAN_BLOCKS) ? partial[t] : 0;
    s[t] = v;
    __syncthreads();
#pragma unroll
    for (int off = 1; off < SCAN_BLK; off <<= 1) {
        int u = (t >= off) ? s[t - off] : 0;
        __syncthreads();
        s[t] += u;
        __syncthreads();
    }
    if (t < N_SCAN_BLOCKS) blockBase[t] = s[t] - v;  // exclusive
    if (t == 0) rowptr[N_NODES] = N_EDGES;           // all dsts are in range
}

// ---------------------------------------------------------------------------
// 2c) per-block exclusive scan + base -> rowptr; also dinv = rsqrt(cnt+1)
// ---------------------------------------------------------------------------
__global__ __launch_bounds__(SCAN_BLK) void scan_apply_kernel(const int* __restrict__ cnt,
                                                              const int* __restrict__ blockBase,
                                                              int* __restrict__ rowptr,
                                                              float* __restrict__ dinv) {
    __shared__ int s[SCAN_BLK];
    int i = blockIdx.x * SCAN_BLK + threadIdx.x;
    int t = threadIdx.x;
    int v = (i < N_NODES) ? cnt[i] : 0;
    s[t] = v;
    __syncthreads();
#pragma unroll
    for (int off = 1; off < SCAN_BLK; off <<= 1) {
        int u = (t >= off) ? s[t - off] : 0;
        __syncthreads();
        s[t] += u;
        __syncthreads();
    }
    if (i < N_NODES) {
        rowptr[i] = blockBase[blockIdx.x] + s[t] - v;  // exclusive
        dinv[i] = rsqrtf((float)(v + 1));              // +1 self-loop
    }
}

// ---------------------------------------------------------------------------
// 3) scatter edges into CSR buckets
// ---------------------------------------------------------------------------
__global__ __launch_bounds__(256) void scatter_kernel(const int* __restrict__ src,
                                                      const int* __restrict__ dst,
                                                      const int* __restrict__ rowptr,
                                                      int* __restrict__ woff,
                                                      int* __restrict__ csr_src) {
    int e = blockIdx.x * 256 + threadIdx.x;
    if (e >= N_EDGES) return;
    int d = dst[e];
    int pos = atomicAdd(&woff[d], 1);
    csr_src[rowptr[d] + pos] = src[e];
}

// ---------------------------------------------------------------------------
// 4) fp32 GEMM, bf16 output:  G[M,128](bf16) = dinv[row] * (X[M,128] @ W[128,128])
//    fp32 inputs + fp32 accumulate; only the stored message buffer is bf16.
//    G is packed 2 bf16 per uint: row = 64 uints.
// ---------------------------------------------------------------------------
__global__ __launch_bounds__(256) void gemm_kernel(const float* __restrict__ X,
                                                   const float* __restrict__ W,
                                                   const float* __restrict__ dinv,
                                                   unsigned int* __restrict__ G, int M) {
    __shared__ float sX[64][132];
    __shared__ float sW[64][132];
    int tid = threadIdx.x;
    int row0 = blockIdx.x * 64;

#pragma unroll
    for (int it = 0; it < 8; ++it) {
        int idx = tid + it * 256;
        int r = idx >> 5, q = idx & 31;
        int grow = row0 + r;
        float4 v = make_float4(0.f, 0.f, 0.f, 0.f);
        if (grow < M) v = *reinterpret_cast<const float4*>(X + grow * 128 + q * 4);
        *reinterpret_cast<float4*>(&sX[r][q * 4]) = v;
    }

    int tx = tid & 15;
    int ty = tid >> 4;
    float acc[4][8];
#pragma unroll
    for (int i = 0; i < 4; ++i)
#pragma unroll
        for (int j = 0; j < 8; ++j) acc[i][j] = 0.f;

    for (int k0 = 0; k0 < 128; k0 += 64) {
        __syncthreads();
#pragma unroll
        for (int it = 0; it < 8; ++it) {
            int idx = tid + it * 256;
            int r = idx >> 5, q = idx & 31;
            *reinterpret_cast<float4*>(&sW[r][q * 4]) =
                *reinterpret_cast<const float4*>(W + (k0 + r) * 128 + q * 4);
        }
        __syncthreads();
#pragma unroll 16
        for (int k = 0; k < 64; ++k) {
            float xv[4];
#pragma unroll
            for (int ri = 0; ri < 4; ++ri) xv[ri] = sX[ty * 4 + ri][k0 + k];
            float4 w0 = *reinterpret_cast<const float4*>(&sW[k][tx * 4]);
            float4 w1 = *reinterpret_cast<const float4*>(&sW[k][64 + tx * 4]);
            float wv[8] = {w0.x, w0.y, w0.z, w0.w, w1.x, w1.y, w1.z, w1.w};
#pragma unroll
            for (int ri = 0; ri < 4; ++ri)
#pragma unroll
                for (int ci = 0; ci < 8; ++ci) acc[ri][ci] += xv[ri] * wv[ci];
        }
    }
#pragma unroll
    for (int ri = 0; ri < 4; ++ri) {
        int grow = row0 + ty * 4 + ri;
        if (grow >= M) continue;
        float sc = dinv[grow];
        // cols tx*4..tx*4+3 -> uint pair at col/2 = tx*2 ; upper half at +32
        uint2 lo, hi;
        lo.x = f2bf(sc * acc[ri][0]) | (f2bf(sc * acc[ri][1]) << 16);
        lo.y = f2bf(sc * acc[ri][2]) | (f2bf(sc * acc[ri][3]) << 16);
        hi.x = f2bf(sc * acc[ri][4]) | (f2bf(sc * acc[ri][5]) << 16);
        hi.y = f2bf(sc * acc[ri][6]) | (f2bf(sc * acc[ri][7]) << 16);
        *reinterpret_cast<uint2*>(G + grow * 64 + tx * 2) = lo;
        *reinterpret_cast<uint2*>(G + grow * 64 + 32 + tx * 2) = hi;
    }
}

// ---------------------------------------------------------------------------
// 5) aggregation on pre-scaled bf16 messages:
//    out[i] = relu( dinv[i] * ( sum_{s in N(i)} G[s] + G[i] ) + b )   [fp32 accum]
//    one wave per node; row = 64 uints -> one dword per lane (fully coalesced).
// ---------------------------------------------------------------------------
__global__ __launch_bounds__(256) void aggregate_kernel(const unsigned int* __restrict__ G,
                                                        const float* __restrict__ dinv,
                                                        const int* __restrict__ rowptr,
                                                        const int* __restrict__ csr_src,
                                                        const float* __restrict__ bias,
                                                        float* __restrict__ Hout, int n) {
    int node = blockIdx.x * 4 + (threadIdx.x >> 6);
    if (node >= n) return;
    int lane = threadIdx.x & 63;
    int start = rowptr[node], end = rowptr[node + 1];

    float di = dinv[node];
    unsigned int gs = G[node * 64 + lane];  // self loop (bf16 pair)
    float bx = bias[lane * 2], by = bias[lane * 2 + 1];

    float ax = bf_lo(gs), ay = bf_hi(gs);
    for (int base = start; base < end; base += 64) {
        int idx = base + lane;
        int s_l = (idx < end) ? csr_src[idx] : 0;
        int nn = min(64, end - base);
#pragma unroll 4
        for (int j = 0; j < nn; ++j) {
            int s = __shfl(s_l, j);
            unsigned int u = G[s * 64 + lane];
            ax += bf_lo(u);
            ay += bf_hi(u);
        }
    }
    float ox = fmaxf(di * ax + bx, 0.f);
    float oy = fmaxf(di * ay + by, 0.f);
    *reinterpret_cast<float2*>(Hout + node * 128 + lane * 2) = make_float2(ox, oy);
}

// ---------------------------------------------------------------------------
// 6) readout: batch is SORTED -> per-graph contiguous node range via binary search
// ---------------------------------------------------------------------------
__global__ __launch_bounds__(256) void readout_kernel(const float* __restrict__ H,
                                                      const int* __restrict__ batch,
                                                      float* __restrict__ out) {
    int g = blockIdx.x;
    int f = threadIdx.x & 127;
    int half = threadIdx.x >> 7;
    const int n = N_NODES;
    auto lb = [&](int key) {
        int lo = 0, hi = n;
        while (lo < hi) {
            int mid = (lo + hi) >> 1;
            if (batch[mid] < key) lo = mid + 1; else hi = mid;
        }
        return lo;
    };
    int start = lb(g), end = lb(g + 1);
    float sum = 0.f, mx = 0.f;  // post-relu values >= 0; empty graph -> 0
    for (int i = start + half; i < end; i += 2) {
        float v = H[i * 128 + f];
        sum += v;
        mx = fmaxf(mx, v);
    }
    __shared__ float ssum[256], smax[256];
    ssum[threadIdx.x] = sum;
    smax[threadIdx.x] = mx;
    __syncthreads();
    if (half == 0) {
        sum += ssum[threadIdx.x + 128];
        mx = fmaxf(mx, smax[threadIdx.x + 128]);
        int cntg = end - start;
        float mean = sum / fmaxf((float)cntg, 1.0f);
        out[g * 384 + f] = sum;
        out[g * 384 + 128 + f] = mx;
        out[g * 384 + 256 + f] = mean;
    }
}

// ---------------------------------------------------------------------------
extern "C" void kernel_launch(void* const* d_in, const int* in_sizes, int n_in,
                              void* d_out, int out_size, void* d_ws, size_t ws_size,
                              hipStream_t stream) {
    const float* x = (const float*)d_in[0];
    const float* W1 = (const float*)d_in[1];
    const float* b1 = (const float*)d_in[2];
    const float* W2 = (const float*)d_in[3];
    const float* b2 = (const float*)d_in[4];
    const int* ei = (const int*)d_in[5];
    const int* batch = (const int*)d_in[6];
    const int* esrc = ei;             // edge_index[0]
    const int* edst = ei + N_EDGES;   // edge_index[1]
    float* out = (float*)d_out;

    char* ws = (char*)d_ws;
    int* cnt       = (int*)(ws + 0);               // 200000 B
    int* woff      = (int*)(ws + 200704);          // 200000 B
    int* rowptr    = (int*)(ws + 401408);          // 200004 B
    float* dinv    = (float*)(ws + 602112);        // 200000 B
    int* partial   = (int*)(ws + 802816);          // 784 B
    int* blockBase = (int*)(ws + 803840);          // 784 B
    int* csr_src   = (int*)(ws + 804864);          // 3.2 MB
    unsigned int* bufG = (unsigned int*)(ws + 4004864);  // 12.8 MB (bf16 G)
    float* bufH    = (float*)(ws + 16804864);      // 25.6 MB (fp32 H, ends ~42.4 MiB)

    hipMemsetAsync(cnt, 0, N_NODES * sizeof(int), stream);
    hipMemsetAsync(woff, 0, N_NODES * sizeof(int), stream);

    count_kernel<<<N_EDGES / 256, 256, 0, stream>>>(edst, cnt);
    scan_partial_kernel<<<N_SCAN_BLOCKS, SCAN_BLK, 0, stream>>>(cnt, partial);
    scan_base_kernel<<<1, SCAN_BLK, 0, stream>>>(partial, blockBase, rowptr);
    scan_apply_kernel<<<N_SCAN_BLOCKS, SCAN_BLK, 0, stream>>>(cnt, blockBase, rowptr, dinv);
    scatter_kernel<<<N_EDGES / 256, 256, 0, stream>>>(esrc, edst, rowptr, woff, csr_src);

    int gemm_blocks = (N_NODES + 63) / 64;
    // layer 1: G1(bf16) = dinv .* (x@W1) ; H1(fp32) = relu(dinv .* (A G1) + b1)
    gemm_kernel<<<gemm_blocks, 256, 0, stream>>>(x, W1, dinv, bufG, N_NODES);
    aggregate_kernel<<<N_NODES / 4, 256, 0, stream>>>(bufG, dinv, rowptr, csr_src, b1, bufH, N_NODES);
    // layer 2: G2(bf16) = dinv .* (H1@W2) ; H2(fp32) = relu(dinv .* (A G2) + b2)
    gemm_kernel<<<gemm_blocks, 256, 0, stream>>>(bufH, W2, dinv, bufG, N_NODES);
    aggregate_kernel<<<N_NODES / 4, 256, 0, stream>>>(bufG, dinv, rowptr, csr_src, b2, bufH, N_NODES);
    // readout
    readout_kernel<<<N_GRAPHS, 256, 0, stream>>>(bufH, batch, out);
}

// Round 11
// 343.351 us; speedup vs baseline: 1.5661x; 1.0880x over previous
//
#include <hip/hip_runtime.h>

#define N_NODES 50000
#define N_EDGES 800000
#define FEAT 128
#define N_GRAPHS 512

#define SCAN_BLK 256
#define N_SCAN_BLOCKS ((N_NODES + SCAN_BLK - 1) / SCAN_BLK)  // 196

// float -> bf16 bits, round-to-nearest-even
__device__ __forceinline__ unsigned int f2bf(float f) {
    unsigned int u = __float_as_uint(f);
    return (u + 0x7fffu + ((u >> 16) & 1u)) >> 16;
}
// bf16 pair (packed in uint) -> two floats
__device__ __forceinline__ float bf_lo(unsigned int u) { return __uint_as_float(u << 16); }
__device__ __forceinline__ float bf_hi(unsigned int u) { return __uint_as_float(u & 0xffff0000u); }

// ---------------------------------------------------------------------------
// 1) count in-degree (real edges only; self-loop handled analytically)
// ---------------------------------------------------------------------------
__global__ __launch_bounds__(256) void count_kernel(const int* __restrict__ dst,
                                                    int* __restrict__ cnt) {
    int e = blockIdx.x * 256 + threadIdx.x;
    if (e < N_EDGES) atomicAdd(&cnt[dst[e]], 1);
}

// ---------------------------------------------------------------------------
// 2a) per-block partial sums of cnt
// ---------------------------------------------------------------------------
__global__ __launch_bounds__(SCAN_BLK) void scan_partial_kernel(const int* __restrict__ cnt,
                                                                int* __restrict__ partial) {
    __shared__ int s[SCAN_BLK];
    int i = blockIdx.x * SCAN_BLK + threadIdx.x;
    s[threadIdx.x] = (i < N_NODES) ? cnt[i] : 0;
    __syncthreads();
#pragma unroll
    for (int off = SCAN_BLK / 2; off > 0; off >>= 1) {
        if (threadIdx.x < off) s[threadIdx.x] += s[threadIdx.x + off];
        __syncthreads();
    }
    if (threadIdx.x == 0) partial[blockIdx.x] = s[0];
}

// ---------------------------------------------------------------------------
// 2b) single block: exclusive scan of the 196 partials -> blockBase
// ---------------------------------------------------------------------------
__global__ __launch_bounds__(SCAN_BLK) void scan_base_kernel(const int* __restrict__ partial,
                                                             int* __restrict__ blockBase,
                                                             int* __restrict__ rowptr) {
    __shared__ int s[SCAN_BLK];
    int t = threadIdx.x;
    int v = (t < N_SCAN_BLOCKS) ? partial[t] : 0;
    s[t] = v;
    __syncthreads();
#pragma unroll
    for (int off = 1; off < SCAN_BLK; off <<= 1) {
        int u = (t >= off) ? s[t - off] : 0;
        __syncthreads();
        s[t] += u;
        __syncthreads();
    }
    if (t < N_SCAN_BLOCKS) blockBase[t] = s[t] - v;  // exclusive
    if (t == 0) rowptr[N_NODES] = N_EDGES;           // all dsts are in range
}

// ---------------------------------------------------------------------------
// 2c) per-block exclusive scan + base -> rowptr; also dinv = rsqrt(cnt+1)
// ---------------------------------------------------------------------------
__global__ __launch_bounds__(SCAN_BLK) void scan_apply_kernel(const int* __restrict__ cnt,
                                                              const int* __restrict__ blockBase,
                                                              int* __restrict__ rowptr,
                                                              float* __restrict__ dinv) {
    __shared__ int s[SCAN_BLK];
    int i = blockIdx.x * SCAN_BLK + threadIdx.x;
    int t = threadIdx.x;
    int v = (i < N_NODES) ? cnt[i] : 0;
    s[t] = v;
    __syncthreads();
#pragma unroll
    for (int off = 1; off < SCAN_BLK; off <<= 1) {
        int u = (t >= off) ? s[t - off] : 0;
        __syncthreads();
        s[t] += u;
        __syncthreads();
    }
    if (i < N_NODES) {
        rowptr[i] = blockBase[blockIdx.x] + s[t] - v;  // exclusive
        dinv[i] = rsqrtf((float)(v + 1));              // +1 self-loop
    }
}

// ---------------------------------------------------------------------------
// 3) scatter edges into CSR buckets
// ---------------------------------------------------------------------------
__global__ __launch_bounds__(256) void scatter_kernel(const int* __restrict__ src,
                                                      const int* __restrict__ dst,
                                                      const int* __restrict__ rowptr,
                                                      int* __restrict__ woff,
                                                      int* __restrict__ csr_src) {
    int e = blockIdx.x * 256 + threadIdx.x;
    if (e >= N_EDGES) return;
    int d = dst[e];
    int pos = atomicAdd(&woff[d], 1);
    csr_src[rowptr[d] + pos] = src[e];
}

// ---------------------------------------------------------------------------
// 4) fp32 GEMM, bf16 output:  G[M,128](bf16) = dinv[row] * (X[M,128] @ W[128,128])
//    fp32 inputs + fp32 accumulate; only the stored message buffer is bf16.
//    G is packed 2 bf16 per uint: row = 64 uints.
// ---------------------------------------------------------------------------
__global__ __launch_bounds__(256) void gemm_kernel(const float* __restrict__ X,
                                                   const float* __restrict__ W,
                                                   const float* __restrict__ dinv,
                                                   unsigned int* __restrict__ G, int M) {
    __shared__ float sX[64][132];
    __shared__ float sW[64][132];
    int tid = threadIdx.x;
    int row0 = blockIdx.x * 64;

#pragma unroll
    for (int it = 0; it < 8; ++it) {
        int idx = tid + it * 256;
        int r = idx >> 5, q = idx & 31;
        int grow = row0 + r;
        float4 v = make_float4(0.f, 0.f, 0.f, 0.f);
        if (grow < M) v = *reinterpret_cast<const float4*>(X + grow * 128 + q * 4);
        *reinterpret_cast<float4*>(&sX[r][q * 4]) = v;
    }

    int tx = tid & 15;
    int ty = tid >> 4;
    float acc[4][8];
#pragma unroll
    for (int i = 0; i < 4; ++i)
#pragma unroll
        for (int j = 0; j < 8; ++j) acc[i][j] = 0.f;

    for (int k0 = 0; k0 < 128; k0 += 64) {
        __syncthreads();
#pragma unroll
        for (int it = 0; it < 8; ++it) {
            int idx = tid + it * 256;
            int r = idx >> 5, q = idx & 31;
            *reinterpret_cast<float4*>(&sW[r][q * 4]) =
                *reinterpret_cast<const float4*>(W + (k0 + r) * 128 + q * 4);
        }
        __syncthreads();
#pragma unroll 16
        for (int k = 0; k < 64; ++k) {
            float xv[4];
#pragma unroll
            for (int ri = 0; ri < 4; ++ri) xv[ri] = sX[ty * 4 + ri][k0 + k];
            float4 w0 = *reinterpret_cast<const float4*>(&sW[k][tx * 4]);
            float4 w1 = *reinterpret_cast<const float4*>(&sW[k][64 + tx * 4]);
            float wv[8] = {w0.x, w0.y, w0.z, w0.w, w1.x, w1.y, w1.z, w1.w};
#pragma unroll
            for (int ri = 0; ri < 4; ++ri)
#pragma unroll
                for (int ci = 0; ci < 8; ++ci) acc[ri][ci] += xv[ri] * wv[ci];
        }
    }
#pragma unroll
    for (int ri = 0; ri < 4; ++ri) {
        int grow = row0 + ty * 4 + ri;
        if (grow >= M) continue;
        float sc = dinv[grow];
        // cols tx*4..tx*4+3 -> uint pair at col/2 = tx*2 ; upper half at +32
        uint2 lo, hi;
        lo.x = f2bf(sc * acc[ri][0]) | (f2bf(sc * acc[ri][1]) << 16);
        lo.y = f2bf(sc * acc[ri][2]) | (f2bf(sc * acc[ri][3]) << 16);
        hi.x = f2bf(sc * acc[ri][4]) | (f2bf(sc * acc[ri][5]) << 16);
        hi.y = f2bf(sc * acc[ri][6]) | (f2bf(sc * acc[ri][7]) << 16);
        *reinterpret_cast<uint2*>(G + grow * 64 + tx * 2) = lo;
        *reinterpret_cast<uint2*>(G + grow * 64 + 32 + tx * 2) = hi;
    }
}

// ---------------------------------------------------------------------------
// 5) aggregation on pre-scaled bf16 messages, 16 lanes per node:
//    out[i] = relu( dinv[i] * ( sum_{s in N(i)} G[s] + G[i] ) + b )   [fp32 accum]
//    4 node-groups per wave -> 4 independent gather chains; each lane reads
//    uint4 (8 bf16), 16 lanes cover the 256B row. Full 16-edge batches are
//    unrolled 8-deep for ~32 outstanding loads/wave (latency hiding).
// ---------------------------------------------------------------------------
__global__ __launch_bounds__(256) void aggregate_kernel(const uint4* __restrict__ G4,
                                                        const float* __restrict__ dinv,
                                                        const int* __restrict__ rowptr,
                                                        const int* __restrict__ csr_src,
                                                        const float* __restrict__ bias,
                                                        float* __restrict__ Hout, int n) {
    int tid = threadIdx.x;
    int node = blockIdx.x * 16 + (tid >> 4);  // 16 nodes per 256-thr block
    int lane16 = tid & 15;
    bool active = node < n;

    int start = active ? rowptr[node] : 0;
    int end = active ? rowptr[node + 1] : 0;

    float a[8] = {0.f, 0.f, 0.f, 0.f, 0.f, 0.f, 0.f, 0.f};
    if (active) {  // self loop row
        uint4 u = G4[node * 16 + lane16];
        a[0] += bf_lo(u.x); a[1] += bf_hi(u.x);
        a[2] += bf_lo(u.y); a[3] += bf_hi(u.y);
        a[4] += bf_lo(u.z); a[5] += bf_hi(u.z);
        a[6] += bf_lo(u.w); a[7] += bf_hi(u.w);
    }

#define ACC_ROW(sidx)                                   \
    {                                                   \
        uint4 u = G4[(sidx) * 16 + lane16];             \
        a[0] += bf_lo(u.x); a[1] += bf_hi(u.x);         \
        a[2] += bf_lo(u.y); a[3] += bf_hi(u.y);         \
        a[4] += bf_lo(u.z); a[5] += bf_hi(u.z);         \
        a[6] += bf_lo(u.w); a[7] += bf_hi(u.w);         \
    }

    for (int base = start; base < end; base += 16) {
        int idx = base + lane16;
        int s_l = (idx < end) ? csr_src[idx] : 0;
        int nn = min(16, end - base);
        if (nn == 16) {
#pragma unroll 8
            for (int j = 0; j < 16; ++j) {
                int s = __shfl(s_l, j, 16);
                ACC_ROW(s);
            }
        } else {
#pragma unroll 4
            for (int j = 0; j < nn; ++j) {
                int s = __shfl(s_l, j, 16);
                ACC_ROW(s);
            }
        }
    }
#undef ACC_ROW

    if (active) {
        float di = dinv[node];
        float4 b0 = *reinterpret_cast<const float4*>(bias + lane16 * 8);
        float4 b1 = *reinterpret_cast<const float4*>(bias + lane16 * 8 + 4);
        float4 o0, o1;
        o0.x = fmaxf(di * a[0] + b0.x, 0.f);
        o0.y = fmaxf(di * a[1] + b0.y, 0.f);
        o0.z = fmaxf(di * a[2] + b0.z, 0.f);
        o0.w = fmaxf(di * a[3] + b0.w, 0.f);
        o1.x = fmaxf(di * a[4] + b1.x, 0.f);
        o1.y = fmaxf(di * a[5] + b1.y, 0.f);
        o1.z = fmaxf(di * a[6] + b1.z, 0.f);
        o1.w = fmaxf(di * a[7] + b1.w, 0.f);
        *reinterpret_cast<float4*>(Hout + node * 128 + lane16 * 8) = o0;
        *reinterpret_cast<float4*>(Hout + node * 128 + lane16 * 8 + 4) = o1;
    }
}

// ---------------------------------------------------------------------------
// 6) readout: batch is SORTED -> per-graph contiguous node range via binary search
// ---------------------------------------------------------------------------
__global__ __launch_bounds__(256) void readout_kernel(const float* __restrict__ H,
                                                      const int* __restrict__ batch,
                                                      float* __restrict__ out) {
    int g = blockIdx.x;
    int f = threadIdx.x & 127;
    int half = threadIdx.x >> 7;
    const int n = N_NODES;
    auto lb = [&](int key) {
        int lo = 0, hi = n;
        while (lo < hi) {
            int mid = (lo + hi) >> 1;
            if (batch[mid] < key) lo = mid + 1; else hi = mid;
        }
        return lo;
    };
    int start = lb(g), end = lb(g + 1);
    float sum = 0.f, mx = 0.f;  // post-relu values >= 0; empty graph -> 0
    for (int i = start + half; i < end; i += 2) {
        float v = H[i * 128 + f];
        sum += v;
        mx = fmaxf(mx, v);
    }
    __shared__ float ssum[256], smax[256];
    ssum[threadIdx.x] = sum;
    smax[threadIdx.x] = mx;
    __syncthreads();
    if (half == 0) {
        sum += ssum[threadIdx.x + 128];
        mx = fmaxf(mx, smax[threadIdx.x + 128]);
        int cntg = end - start;
        float mean = sum / fmaxf((float)cntg, 1.0f);
        out[g * 384 + f] = sum;
        out[g * 384 + 128 + f] = mx;
        out[g * 384 + 256 + f] = mean;
    }
}

// ---------------------------------------------------------------------------
extern "C" void kernel_launch(void* const* d_in, const int* in_sizes, int n_in,
                              void* d_out, int out_size, void* d_ws, size_t ws_size,
                              hipStream_t stream) {
    const float* x = (const float*)d_in[0];
    const float* W1 = (const float*)d_in[1];
    const float* b1 = (const float*)d_in[2];
    const float* W2 = (const float*)d_in[3];
    const float* b2 = (const float*)d_in[4];
    const int* ei = (const int*)d_in[5];
    const int* batch = (const int*)d_in[6];
    const int* esrc = ei;             // edge_index[0]
    const int* edst = ei + N_EDGES;   // edge_index[1]
    float* out = (float*)d_out;

    char* ws = (char*)d_ws;
    int* cnt       = (int*)(ws + 0);               // 200000 B
    int* woff      = (int*)(ws + 200704);          // 200000 B
    int* rowptr    = (int*)(ws + 401408);          // 200004 B
    float* dinv    = (float*)(ws + 602112);        // 200000 B
    int* partial   = (int*)(ws + 802816);          // 784 B
    int* blockBase = (int*)(ws + 803840);          // 784 B
    int* csr_src   = (int*)(ws + 804864);          // 3.2 MB
    unsigned int* bufG = (unsigned int*)(ws + 4004864);  // 12.8 MB (bf16 G)
    float* bufH    = (float*)(ws + 16804864);      // 25.6 MB (fp32 H, ends ~42.4 MiB)

    hipMemsetAsync(cnt, 0, N_NODES * sizeof(int), stream);
    hipMemsetAsync(woff, 0, N_NODES * sizeof(int), stream);

    count_kernel<<<N_EDGES / 256, 256, 0, stream>>>(edst, cnt);
    scan_partial_kernel<<<N_SCAN_BLOCKS, SCAN_BLK, 0, stream>>>(cnt, partial);
    scan_base_kernel<<<1, SCAN_BLK, 0, stream>>>(partial, blockBase, rowptr);
    scan_apply_kernel<<<N_SCAN_BLOCKS, SCAN_BLK, 0, stream>>>(cnt, blockBase, rowptr, dinv);
    scatter_kernel<<<N_EDGES / 256, 256, 0, stream>>>(esrc, edst, rowptr, woff, csr_src);

    int gemm_blocks = (N_NODES + 63) / 64;
    int agg_blocks = (N_NODES + 15) / 16;
    // layer 1: G1(bf16) = dinv .* (x@W1) ; H1(fp32) = relu(dinv .* (A G1) + b1)
    gemm_kernel<<<gemm_blocks, 256, 0, stream>>>(x, W1, dinv, bufG, N_NODES);
    aggregate_kernel<<<agg_blocks, 256, 0, stream>>>((const uint4*)bufG, dinv, rowptr, csr_src, b1, bufH, N_NODES);
    // layer 2: G2(bf16) = dinv .* (H1@W2) ; H2(fp32) = relu(dinv .* (A G2) + b2)
    gemm_kernel<<<gemm_blocks, 256, 0, stream>>>(bufH, W2, dinv, bufG, N_NODES);
    aggregate_kernel<<<agg_blocks, 256, 0, stream>>>((const uint4*)bufG, dinv, rowptr, csr_src, b2, bufH, N_NODES);
    // readout
    readout_kernel<<<N_GRAPHS, 256, 0, stream>>>(bufH, batch, out);
}

// Round 14
// 334.190 us; speedup vs baseline: 1.6090x; 1.0274x over previous
//
#include <hip/hip_runtime.h>

#define N_NODES 50000
#define N_EDGES 800000
#define FEAT 128
#define N_GRAPHS 512

#define SCAN_BLK 256
#define N_SCAN_BLOCKS ((N_NODES + SCAN_BLK - 1) / SCAN_BLK)  // 196

// float -> bf16 bits, round-to-nearest-even
__device__ __forceinline__ unsigned int f2bf(float f) {
    unsigned int u = __float_as_uint(f);
    return (u + 0x7fffu + ((u >> 16) & 1u)) >> 16;
}
// bf16 pair (packed in uint) -> two floats
__device__ __forceinline__ float bf_lo(unsigned int u) { return __uint_as_float(u << 16); }
__device__ __forceinline__ float bf_hi(unsigned int u) { return __uint_as_float(u & 0xffff0000u); }

// ---------------------------------------------------------------------------
// 1) count in-degree. Streaming dst reads are non-temporal (don't pollute L2).
// ---------------------------------------------------------------------------
__global__ __launch_bounds__(256) void count_kernel(const int* __restrict__ dst,
                                                    int* __restrict__ cnt) {
    int e = blockIdx.x * 256 + threadIdx.x;
    if (e < N_EDGES) atomicAdd(&cnt[__builtin_nontemporal_load(dst + e)], 1);
}

// ---------------------------------------------------------------------------
// 2a) per-block partial sums of cnt
// ---------------------------------------------------------------------------
__global__ __launch_bounds__(SCAN_BLK) void scan_partial_kernel(const int* __restrict__ cnt,
                                                                int* __restrict__ partial) {
    __shared__ int s[SCAN_BLK];
    int i = blockIdx.x * SCAN_BLK + threadIdx.x;
    s[threadIdx.x] = (i < N_NODES) ? cnt[i] : 0;
    __syncthreads();
#pragma unroll
    for (int off = SCAN_BLK / 2; off > 0; off >>= 1) {
        if (threadIdx.x < off) s[threadIdx.x] += s[threadIdx.x + off];
        __syncthreads();
    }
    if (threadIdx.x == 0) partial[blockIdx.x] = s[0];
}

// ---------------------------------------------------------------------------
// 2b) fused: per-block base (reduce over partials < bid) + exclusive scan ->
//     rowptr; also dinv = rsqrt(cnt+1). Replaces separate scan_base kernel.
// ---------------------------------------------------------------------------
__global__ __launch_bounds__(SCAN_BLK) void scan_apply_kernel(const int* __restrict__ cnt,
                                                              const int* __restrict__ partial,
                                                              int* __restrict__ rowptr,
                                                              float* __restrict__ dinv) {
    __shared__ int s[SCAN_BLK];
    __shared__ int sbase;
    int t = threadIdx.x;
    int bid = blockIdx.x;

    // base = sum of partial[0..bid-1]   (bid <= 195 < SCAN_BLK)
    s[t] = (t < bid) ? partial[t] : 0;
    __syncthreads();
#pragma unroll
    for (int off = SCAN_BLK / 2; off > 0; off >>= 1) {
        if (t < off) s[t] += s[t + off];
        __syncthreads();
    }
    if (t == 0) sbase = s[0];
    __syncthreads();

    int i = bid * SCAN_BLK + t;
    int v = (i < N_NODES) ? cnt[i] : 0;
    s[t] = v;
    __syncthreads();
#pragma unroll
    for (int off = 1; off < SCAN_BLK; off <<= 1) {
        int u = (t >= off) ? s[t - off] : 0;
        __syncthreads();
        s[t] += u;
        __syncthreads();
    }
    if (i < N_NODES) {
        rowptr[i] = sbase + s[t] - v;      // exclusive prefix
        dinv[i] = rsqrtf((float)(v + 1));  // +1 self-loop
    }
    if (bid == 0 && t == 0) rowptr[N_NODES] = N_EDGES;  // all dsts in range
}

// ---------------------------------------------------------------------------
// 3) scatter edges into CSR buckets (ushort entries; node ids < 65536).
//    Streaming src/dst reads are non-temporal so the scattered csr lines stay
//    L2-resident and write-backs merge (kills the 17x write amplification).
// ---------------------------------------------------------------------------
__global__ __launch_bounds__(256) void scatter_kernel(const int* __restrict__ src,
                                                      const int* __restrict__ dst,
                                                      const int* __restrict__ rowptr,
                                                      int* __restrict__ woff,
                                                      unsigned short* __restrict__ csr_src) {
    int e = blockIdx.x * 256 + threadIdx.x;
    if (e >= N_EDGES) return;
    int s = __builtin_nontemporal_load(src + e);
    int d = __builtin_nontemporal_load(dst + e);
    int pos = atomicAdd(&woff[d], 1);
    csr_src[rowptr[d] + pos] = (unsigned short)s;
}

// ---------------------------------------------------------------------------
// 4) fp32 GEMM, bf16 output:  G[M,128](bf16) = dinv[row] * (X[M,128] @ W[128,128])
// ---------------------------------------------------------------------------
__global__ __launch_bounds__(256) void gemm_kernel(const float* __restrict__ X,
                                                   const float* __restrict__ W,
                                                   const float* __restrict__ dinv,
                                                   unsigned int* __restrict__ G, int M) {
    __shared__ float sX[64][132];
    __shared__ float sW[64][132];
    int tid = threadIdx.x;
    int row0 = blockIdx.x * 64;

#pragma unroll
    for (int it = 0; it < 8; ++it) {
        int idx = tid + it * 256;
        int r = idx >> 5, q = idx & 31;
        int grow = row0 + r;
        float4 v = make_float4(0.f, 0.f, 0.f, 0.f);
        if (grow < M) v = *reinterpret_cast<const float4*>(X + grow * 128 + q * 4);
        *reinterpret_cast<float4*>(&sX[r][q * 4]) = v;
    }

    int tx = tid & 15;
    int ty = tid >> 4;
    float acc[4][8];
#pragma unroll
    for (int i = 0; i < 4; ++i)
#pragma unroll
        for (int j = 0; j < 8; ++j) acc[i][j] = 0.f;

    for (int k0 = 0; k0 < 128; k0 += 64) {
        __syncthreads();
#pragma unroll
        for (int it = 0; it < 8; ++it) {
            int idx = tid + it * 256;
            int r = idx >> 5, q = idx & 31;
            *reinterpret_cast<float4*>(&sW[r][q * 4]) =
                *reinterpret_cast<const float4*>(W + (k0 + r) * 128 + q * 4);
        }
        __syncthreads();
#pragma unroll 16
        for (int k = 0; k < 64; ++k) {
            float xv[4];
#pragma unroll
            for (int ri = 0; ri < 4; ++ri) xv[ri] = sX[ty * 4 + ri][k0 + k];
            float4 w0 = *reinterpret_cast<const float4*>(&sW[k][tx * 4]);
            float4 w1 = *reinterpret_cast<const float4*>(&sW[k][64 + tx * 4]);
            float wv[8] = {w0.x, w0.y, w0.z, w0.w, w1.x, w1.y, w1.z, w1.w};
#pragma unroll
            for (int ri = 0; ri < 4; ++ri)
#pragma unroll
                for (int ci = 0; ci < 8; ++ci) acc[ri][ci] += xv[ri] * wv[ci];
        }
    }
#pragma unroll
    for (int ri = 0; ri < 4; ++ri) {
        int grow = row0 + ty * 4 + ri;
        if (grow >= M) continue;
        float sc = dinv[grow];
        uint2 lo, hi;
        lo.x = f2bf(sc * acc[ri][0]) | (f2bf(sc * acc[ri][1]) << 16);
        lo.y = f2bf(sc * acc[ri][2]) | (f2bf(sc * acc[ri][3]) << 16);
        hi.x = f2bf(sc * acc[ri][4]) | (f2bf(sc * acc[ri][5]) << 16);
        hi.y = f2bf(sc * acc[ri][6]) | (f2bf(sc * acc[ri][7]) << 16);
        *reinterpret_cast<uint2*>(G + grow * 64 + tx * 2) = lo;
        *reinterpret_cast<uint2*>(G + grow * 64 + 32 + tx * 2) = hi;
    }
}

// ---------------------------------------------------------------------------
// 5) aggregation on pre-scaled bf16 messages, 16 lanes per node (uint4 rows).
// ---------------------------------------------------------------------------
__global__ __launch_bounds__(256) void aggregate_kernel(const uint4* __restrict__ G4,
                                                        const float* __restrict__ dinv,
                                                        const int* __restrict__ rowptr,
                                                        const unsigned short* __restrict__ csr_src,
                                                        const float* __restrict__ bias,
                                                        float* __restrict__ Hout, int n) {
    int tid = threadIdx.x;
    int node = blockIdx.x * 16 + (tid >> 4);  // 16 nodes per 256-thr block
    int lane16 = tid & 15;
    bool active = node < n;

    int start = active ? rowptr[node] : 0;
    int end = active ? rowptr[node + 1] : 0;

    float a[8] = {0.f, 0.f, 0.f, 0.f, 0.f, 0.f, 0.f, 0.f};
    if (active) {  // self loop row
        uint4 u = G4[node * 16 + lane16];
        a[0] += bf_lo(u.x); a[1] += bf_hi(u.x);
        a[2] += bf_lo(u.y); a[3] += bf_hi(u.y);
        a[4] += bf_lo(u.z); a[5] += bf_hi(u.z);
        a[6] += bf_lo(u.w); a[7] += bf_hi(u.w);
    }

#define ACC_ROW(sidx)                                   \
    {                                                   \
        uint4 u = G4[(sidx) * 16 + lane16];             \
        a[0] += bf_lo(u.x); a[1] += bf_hi(u.x);         \
        a[2] += bf_lo(u.y); a[3] += bf_hi(u.y);         \
        a[4] += bf_lo(u.z); a[5] += bf_hi(u.z);         \
        a[6] += bf_lo(u.w); a[7] += bf_hi(u.w);         \
    }

    for (int base = start; base < end; base += 16) {
        int idx = base + lane16;
        int s_l = (idx < end) ? (int)csr_src[idx] : 0;
        int nn = min(16, end - base);
        if (nn == 16) {
#pragma unroll 8
            for (int j = 0; j < 16; ++j) {
                int s = __shfl(s_l, j, 16);
                ACC_ROW(s);
            }
        } else {
#pragma unroll 4
            for (int j = 0; j < nn; ++j) {
                int s = __shfl(s_l, j, 16);
                ACC_ROW(s);
            }
        }
    }
#undef ACC_ROW

    if (active) {
        float di = dinv[node];
        float4 b0 = *reinterpret_cast<const float4*>(bias + lane16 * 8);
        float4 b1 = *reinterpret_cast<const float4*>(bias + lane16 * 8 + 4);
        float4 o0, o1;
        o0.x = fmaxf(di * a[0] + b0.x, 0.f);
        o0.y = fmaxf(di * a[1] + b0.y, 0.f);
        o0.z = fmaxf(di * a[2] + b0.z, 0.f);
        o0.w = fmaxf(di * a[3] + b0.w, 0.f);
        o1.x = fmaxf(di * a[4] + b1.x, 0.f);
        o1.y = fmaxf(di * a[5] + b1.y, 0.f);
        o1.z = fmaxf(di * a[6] + b1.z, 0.f);
        o1.w = fmaxf(di * a[7] + b1.w, 0.f);
        *reinterpret_cast<float4*>(Hout + node * 128 + lane16 * 8) = o0;
        *reinterpret_cast<float4*>(Hout + node * 128 + lane16 * 8 + 4) = o1;
    }
}

// ---------------------------------------------------------------------------
// 6) readout: batch is SORTED -> per-graph contiguous node range via binary search
// ---------------------------------------------------------------------------
__global__ __launch_bounds__(256) void readout_kernel(const float* __restrict__ H,
                                                      const int* __restrict__ batch,
                                                      float* __restrict__ out) {
    int g = blockIdx.x;
    int f = threadIdx.x & 127;
    int half = threadIdx.x >> 7;
    const int n = N_NODES;
    auto lb = [&](int key) {
        int lo = 0, hi = n;
        while (lo < hi) {
            int mid = (lo + hi) >> 1;
            if (batch[mid] < key) lo = mid + 1; else hi = mid;
        }
        return lo;
    };
    int start = lb(g), end = lb(g + 1);
    float sum = 0.f, mx = 0.f;  // post-relu values >= 0; empty graph -> 0
    for (int i = start + half; i < end; i += 2) {
        float v = H[i * 128 + f];
        sum += v;
        mx = fmaxf(mx, v);
    }
    __shared__ float ssum[256], smax[256];
    ssum[threadIdx.x] = sum;
    smax[threadIdx.x] = mx;
    __syncthreads();
    if (half == 0) {
        sum += ssum[threadIdx.x + 128];
        mx = fmaxf(mx, smax[threadIdx.x + 128]);
        int cntg = end - start;
        float mean = sum / fmaxf((float)cntg, 1.0f);
        out[g * 384 + f] = sum;
        out[g * 384 + 128 + f] = mx;
        out[g * 384 + 256 + f] = mean;
    }
}

// ---------------------------------------------------------------------------
extern "C" void kernel_launch(void* const* d_in, const int* in_sizes, int n_in,
                              void* d_out, int out_size, void* d_ws, size_t ws_size,
                              hipStream_t stream) {
    const float* x = (const float*)d_in[0];
    const float* W1 = (const float*)d_in[1];
    const float* b1 = (const float*)d_in[2];
    const float* W2 = (const float*)d_in[3];
    const float* b2 = (const float*)d_in[4];
    const int* ei = (const int*)d_in[5];
    const int* batch = (const int*)d_in[6];
    const int* esrc = ei;             // edge_index[0]
    const int* edst = ei + N_EDGES;   // edge_index[1]
    float* out = (float*)d_out;

    char* ws = (char*)d_ws;
    int* cnt       = (int*)(ws + 0);               // 200000 B
    int* woff      = (int*)(ws + 200704);          // 200000 B
    int* rowptr    = (int*)(ws + 401408);          // 200004 B
    float* dinv    = (float*)(ws + 602112);        // 200000 B
    int* partial   = (int*)(ws + 802816);          // 784 B
    unsigned short* csr_src = (unsigned short*)(ws + 804864);  // 1.6 MB (ushort)
    unsigned int* bufG = (unsigned int*)(ws + 2404864);        // 12.8 MB (bf16 G)
    float* bufH    = (float*)(ws + 15204864);                  // 25.6 MB (fp32 H)

    hipMemsetAsync(cnt, 0, N_NODES * sizeof(int), stream);
    hipMemsetAsync(woff, 0, N_NODES * sizeof(int), stream);

    count_kernel<<<N_EDGES / 256, 256, 0, stream>>>(edst, cnt);
    scan_partial_kernel<<<N_SCAN_BLOCKS, SCAN_BLK, 0, stream>>>(cnt, partial);
    scan_apply_kernel<<<N_SCAN_BLOCKS, SCAN_BLK, 0, stream>>>(cnt, partial, rowptr, dinv);
    scatter_kernel<<<N_EDGES / 256, 256, 0, stream>>>(esrc, edst, rowptr, woff, csr_src);

    int gemm_blocks = (N_NODES + 63) / 64;
    int agg_blocks = (N_NODES + 15) / 16;
    // layer 1: G1(bf16) = dinv .* (x@W1) ; H1(fp32) = relu(dinv .* (A G1) + b1)
    gemm_kernel<<<gemm_blocks, 256, 0, stream>>>(x, W1, dinv, bufG, N_NODES);
    aggregate_kernel<<<agg_blocks, 256, 0, stream>>>((const uint4*)bufG, dinv, rowptr, csr_src, b1, bufH, N_NODES);
    // layer 2: G2(bf16) = dinv .* (H1@W2) ; H2(fp32) = relu(dinv .* (A G2) + b2)
    gemm_kernel<<<gemm_blocks, 256, 0, stream>>>(bufH, W2, dinv, bufG, N_NODES);
    aggregate_kernel<<<agg_blocks, 256, 0, stream>>>((const uint4*)bufG, dinv, rowptr, csr_src, b2, bufH, N_NODES);
    // readout
    readout_kernel<<<N_GRAPHS, 256, 0, stream>>>(bufH, batch, out);
}

// Round 15
// 330.811 us; speedup vs baseline: 1.6255x; 1.0102x over previous
//
#include <hip/hip_runtime.h>

#define N_NODES 50000
#define N_EDGES 800000
#define FEAT 128
#define N_GRAPHS 512

#define SCAN_BLK 256
#define N_SCAN_BLOCKS ((N_NODES + SCAN_BLK - 1) / SCAN_BLK)  // 196
#define LDK 136  // padded bf16 k-stride (272 B rows: 16B-aligned, bank-uniform)

typedef __attribute__((ext_vector_type(8))) short short8;
typedef __attribute__((ext_vector_type(4))) float f32x4;

// float -> bf16 bits, round-to-nearest-even
__device__ __forceinline__ unsigned int f2bf(float f) {
    unsigned int u = __float_as_uint(f);
    return (u + 0x7fffu + ((u >> 16) & 1u)) >> 16;
}
// bf16 pair (packed in uint) -> two floats
__device__ __forceinline__ float bf_lo(unsigned int u) { return __uint_as_float(u << 16); }
__device__ __forceinline__ float bf_hi(unsigned int u) { return __uint_as_float(u & 0xffff0000u); }

// ---------------------------------------------------------------------------
// 1) count in-degree
// ---------------------------------------------------------------------------
__global__ __launch_bounds__(256) void count_kernel(const int* __restrict__ dst,
                                                    int* __restrict__ cnt) {
    int e = blockIdx.x * 256 + threadIdx.x;
    if (e < N_EDGES) atomicAdd(&cnt[__builtin_nontemporal_load(dst + e)], 1);
}

// ---------------------------------------------------------------------------
// 2a) per-block partial sums of cnt
// ---------------------------------------------------------------------------
__global__ __launch_bounds__(SCAN_BLK) void scan_partial_kernel(const int* __restrict__ cnt,
                                                                int* __restrict__ partial) {
    __shared__ int s[SCAN_BLK];
    int i = blockIdx.x * SCAN_BLK + threadIdx.x;
    s[threadIdx.x] = (i < N_NODES) ? cnt[i] : 0;
    __syncthreads();
#pragma unroll
    for (int off = SCAN_BLK / 2; off > 0; off >>= 1) {
        if (threadIdx.x < off) s[threadIdx.x] += s[threadIdx.x + off];
        __syncthreads();
    }
    if (threadIdx.x == 0) partial[blockIdx.x] = s[0];
}

// ---------------------------------------------------------------------------
// 2b) fused base + exclusive scan -> rowptr; dinv = rsqrt(cnt+1)
// ---------------------------------------------------------------------------
__global__ __launch_bounds__(SCAN_BLK) void scan_apply_kernel(const int* __restrict__ cnt,
                                                              const int* __restrict__ partial,
                                                              int* __restrict__ rowptr,
                                                              float* __restrict__ dinv) {
    __shared__ int s[SCAN_BLK];
    __shared__ int sbase;
    int t = threadIdx.x;
    int bid = blockIdx.x;

    s[t] = (t < bid) ? partial[t] : 0;
    __syncthreads();
#pragma unroll
    for (int off = SCAN_BLK / 2; off > 0; off >>= 1) {
        if (t < off) s[t] += s[t + off];
        __syncthreads();
    }
    if (t == 0) sbase = s[0];
    __syncthreads();

    int i = bid * SCAN_BLK + t;
    int v = (i < N_NODES) ? cnt[i] : 0;
    s[t] = v;
    __syncthreads();
#pragma unroll
    for (int off = 1; off < SCAN_BLK; off <<= 1) {
        int u = (t >= off) ? s[t - off] : 0;
        __syncthreads();
        s[t] += u;
        __syncthreads();
    }
    if (i < N_NODES) {
        rowptr[i] = sbase + s[t] - v;
        dinv[i] = rsqrtf((float)(v + 1));
    }
    if (bid == 0 && t == 0) rowptr[N_NODES] = N_EDGES;
}

// ---------------------------------------------------------------------------
// 3) scatter edges into CSR buckets (ushort entries)
// ---------------------------------------------------------------------------
__global__ __launch_bounds__(256) void scatter_kernel(const int* __restrict__ src,
                                                      const int* __restrict__ dst,
                                                      const int* __restrict__ rowptr,
                                                      int* __restrict__ woff,
                                                      unsigned short* __restrict__ csr_src) {
    int e = blockIdx.x * 256 + threadIdx.x;
    if (e >= N_EDGES) return;
    int s = __builtin_nontemporal_load(src + e);
    int d = __builtin_nontemporal_load(dst + e);
    int pos = atomicAdd(&woff[d], 1);
    csr_src[rowptr[d] + pos] = (unsigned short)s;
}

// ---------------------------------------------------------------------------
// 3b) W[128][128] fp32 -> Wt[128][128] bf16 transposed (k contiguous per row)
// ---------------------------------------------------------------------------
__global__ __launch_bounds__(256) void wt_kernel(const float* __restrict__ W,
                                                 unsigned short* __restrict__ Wt) {
    int t = threadIdx.x;
#pragma unroll
    for (int i = 0; i < 64; ++i) {
        int idx = t + 256 * i;           // 16384 elements
        int k = idx >> 7, n = idx & 127;
        Wt[n * 128 + k] = (unsigned short)f2bf(W[idx]);  // coalesced read, scattered write (32 KB, L2)
    }
}

// ---------------------------------------------------------------------------
// 4) bf16 MFMA GEMM: G16[M,128](bf16) = dinv[row] * (X[M,128] @ W)
//    A-frag: lane l -> row l&15, k = 8*(l>>4)+j (contiguous short8 from sX)
//    B-frag: lane l -> col l&15, k = 8*(l>>4)+j (contiguous short8 from sW=W^T)
//    C/D (m89-verified): col = lane&15, row = (lane>>4)*4 + reg
//    Per wave: 16 rows x 128 cols = 8 col-blocks x 4 k-chunks = 32 mfma.
// ---------------------------------------------------------------------------
__global__ __launch_bounds__(256) void gemm_kernel(const float* __restrict__ X,
                                                   const unsigned short* __restrict__ Wt,
                                                   const float* __restrict__ dinv,
                                                   unsigned short* __restrict__ G16, int M) {
    __shared__ unsigned short sX[64][LDK];   // 17408 B
    __shared__ unsigned short sW[128][LDK];  // 34816 B  (total 52224 -> 3 blocks/CU)
    int tid = threadIdx.x;
    int row0 = blockIdx.x * 64;

    // stage X tile (fp32 -> bf16), coalesced float4 reads
#pragma unroll
    for (int it = 0; it < 8; ++it) {
        int idx = tid + it * 256;       // 2048 float4 slots
        int r = idx >> 5, q = idx & 31;
        int grow = row0 + r;
        float4 v = make_float4(0.f, 0.f, 0.f, 0.f);
        if (grow < M) v = *reinterpret_cast<const float4*>(X + grow * 128 + q * 4);
        uint2 pk;
        pk.x = f2bf(v.x) | (f2bf(v.y) << 16);
        pk.y = f2bf(v.z) | (f2bf(v.w) << 16);
        *reinterpret_cast<uint2*>(&sX[r][q * 4]) = pk;
    }
    // stage Wt (already bf16), coalesced uint2 reads
#pragma unroll
    for (int it = 0; it < 16; ++it) {
        int idx = tid + it * 256;       // 4096 uint2 slots
        int n = idx >> 5, q = idx & 31;
        uint2 v = *reinterpret_cast<const uint2*>(Wt + n * 128 + q * 4);
        *reinterpret_cast<uint2*>(&sW[n][q * 4]) = v;
    }
    __syncthreads();

    int lane = tid & 63;
    int w = tid >> 6;       // wave id -> rows 16w..16w+15
    int r = lane & 15;
    int g = lane >> 4;      // k-subgroup (8 k each)

    short8 av[4];
#pragma unroll
    for (int g2 = 0; g2 < 4; ++g2)
        av[g2] = *reinterpret_cast<const short8*>(&sX[16 * w + r][g2 * 32 + g * 8]);

    // epilogue row info (independent of nb)
    float dv[4];
    int gr[4];
#pragma unroll
    for (int reg = 0; reg < 4; ++reg) {
        gr[reg] = row0 + 16 * w + 4 * g + reg;
        dv[reg] = (gr[reg] < M) ? dinv[gr[reg]] : 0.f;
    }

#pragma unroll
    for (int nb = 0; nb < 8; ++nb) {
        f32x4 c = {0.f, 0.f, 0.f, 0.f};
#pragma unroll
        for (int g2 = 0; g2 < 4; ++g2) {
            short8 bv = *reinterpret_cast<const short8*>(&sW[nb * 16 + r][g2 * 32 + g * 8]);
            c = __builtin_amdgcn_mfma_f32_16x16x32_bf16(av[g2], bv, c, 0, 0, 0);
        }
#pragma unroll
        for (int reg = 0; reg < 4; ++reg) {
            if (gr[reg] < M)
                G16[gr[reg] * 128 + nb * 16 + r] = (unsigned short)f2bf(dv[reg] * c[reg]);
        }
    }
}

// ---------------------------------------------------------------------------
// 5) aggregation on pre-scaled bf16 messages, 16 lanes per node (uint4 rows).
// ---------------------------------------------------------------------------
__global__ __launch_bounds__(256) void aggregate_kernel(const uint4* __restrict__ G4,
                                                        const float* __restrict__ dinv,
                                                        const int* __restrict__ rowptr,
                                                        const unsigned short* __restrict__ csr_src,
                                                        const float* __restrict__ bias,
                                                        float* __restrict__ Hout, int n) {
    int tid = threadIdx.x;
    int node = blockIdx.x * 16 + (tid >> 4);
    int lane16 = tid & 15;
    bool active = node < n;

    int start = active ? rowptr[node] : 0;
    int end = active ? rowptr[node + 1] : 0;

    float a[8] = {0.f, 0.f, 0.f, 0.f, 0.f, 0.f, 0.f, 0.f};
    if (active) {  // self loop row
        uint4 u = G4[node * 16 + lane16];
        a[0] += bf_lo(u.x); a[1] += bf_hi(u.x);
        a[2] += bf_lo(u.y); a[3] += bf_hi(u.y);
        a[4] += bf_lo(u.z); a[5] += bf_hi(u.z);
        a[6] += bf_lo(u.w); a[7] += bf_hi(u.w);
    }

#define ACC_ROW(sidx)                                   \
    {                                                   \
        uint4 u = G4[(sidx) * 16 + lane16];             \
        a[0] += bf_lo(u.x); a[1] += bf_hi(u.x);         \
        a[2] += bf_lo(u.y); a[3] += bf_hi(u.y);         \
        a[4] += bf_lo(u.z); a[5] += bf_hi(u.z);         \
        a[6] += bf_lo(u.w); a[7] += bf_hi(u.w);         \
    }

    for (int base = start; base < end; base += 16) {
        int idx = base + lane16;
        int s_l = (idx < end) ? (int)csr_src[idx] : 0;
        int nn = min(16, end - base);
        if (nn == 16) {
#pragma unroll 8
            for (int j = 0; j < 16; ++j) {
                int s = __shfl(s_l, j, 16);
                ACC_ROW(s);
            }
        } else {
#pragma unroll 4
            for (int j = 0; j < nn; ++j) {
                int s = __shfl(s_l, j, 16);
                ACC_ROW(s);
            }
        }
    }
#undef ACC_ROW

    if (active) {
        float di = dinv[node];
        float4 b0 = *reinterpret_cast<const float4*>(bias + lane16 * 8);
        float4 b1 = *reinterpret_cast<const float4*>(bias + lane16 * 8 + 4);
        float4 o0, o1;
        o0.x = fmaxf(di * a[0] + b0.x, 0.f);
        o0.y = fmaxf(di * a[1] + b0.y, 0.f);
        o0.z = fmaxf(di * a[2] + b0.z, 0.f);
        o0.w = fmaxf(di * a[3] + b0.w, 0.f);
        o1.x = fmaxf(di * a[4] + b1.x, 0.f);
        o1.y = fmaxf(di * a[5] + b1.y, 0.f);
        o1.z = fmaxf(di * a[6] + b1.z, 0.f);
        o1.w = fmaxf(di * a[7] + b1.w, 0.f);
        *reinterpret_cast<float4*>(Hout + node * 128 + lane16 * 8) = o0;
        *reinterpret_cast<float4*>(Hout + node * 128 + lane16 * 8 + 4) = o1;
    }
}

// ---------------------------------------------------------------------------
// 6) readout: batch sorted -> per-graph contiguous range via binary search
// ---------------------------------------------------------------------------
__global__ __launch_bounds__(256) void readout_kernel(const float* __restrict__ H,
                                                      const int* __restrict__ batch,
                                                      float* __restrict__ out) {
    int g = blockIdx.x;
    int f = threadIdx.x & 127;
    int half = threadIdx.x >> 7;
    const int n = N_NODES;
    auto lb = [&](int key) {
        int lo = 0, hi = n;
        while (lo < hi) {
            int mid = (lo + hi) >> 1;
            if (batch[mid] < key) lo = mid + 1; else hi = mid;
        }
        return lo;
    };
    int start = lb(g), end = lb(g + 1);
    float sum = 0.f, mx = 0.f;
    for (int i = start + half; i < end; i += 2) {
        float v = H[i * 128 + f];
        sum += v;
        mx = fmaxf(mx, v);
    }
    __shared__ float ssum[256], smax[256];
    ssum[threadIdx.x] = sum;
    smax[threadIdx.x] = mx;
    __syncthreads();
    if (half == 0) {
        sum += ssum[threadIdx.x + 128];
        mx = fmaxf(mx, smax[threadIdx.x + 128]);
        int cntg = end - start;
        float mean = sum / fmaxf((float)cntg, 1.0f);
        out[g * 384 + f] = sum;
        out[g * 384 + 128 + f] = mx;
        out[g * 384 + 256 + f] = mean;
    }
}

// ---------------------------------------------------------------------------
extern "C" void kernel_launch(void* const* d_in, const int* in_sizes, int n_in,
                              void* d_out, int out_size, void* d_ws, size_t ws_size,
                              hipStream_t stream) {
    const float* x = (const float*)d_in[0];
    const float* W1 = (const float*)d_in[1];
    const float* b1 = (const float*)d_in[2];
    const float* W2 = (const float*)d_in[3];
    const float* b2 = (const float*)d_in[4];
    const int* ei = (const int*)d_in[5];
    const int* batch = (const int*)d_in[6];
    const int* esrc = ei;
    const int* edst = ei + N_EDGES;
    float* out = (float*)d_out;

    char* ws = (char*)d_ws;
    int* cnt       = (int*)(ws + 0);               // 200000 B
    int* woff      = (int*)(ws + 200704);          // 200000 B
    int* rowptr    = (int*)(ws + 401408);          // 200004 B
    float* dinv    = (float*)(ws + 602112);        // 200000 B
    int* partial   = (int*)(ws + 802816);          // 784 B
    unsigned short* csr_src = (unsigned short*)(ws + 804864);  // 1.6 MB
    unsigned short* bufG = (unsigned short*)(ws + 2404864);    // 12.8 MB (bf16 G)
    float* bufH    = (float*)(ws + 15204864);                  // 25.6 MB (fp32 H)
    unsigned short* wt1 = (unsigned short*)(ws + 40804864);    // 32 KB
    unsigned short* wt2 = (unsigned short*)(ws + 40837632);    // 32 KB

    hipMemsetAsync(cnt, 0, N_NODES * sizeof(int), stream);
    hipMemsetAsync(woff, 0, N_NODES * sizeof(int), stream);

    count_kernel<<<N_EDGES / 256, 256, 0, stream>>>(edst, cnt);
    scan_partial_kernel<<<N_SCAN_BLOCKS, SCAN_BLK, 0, stream>>>(cnt, partial);
    scan_apply_kernel<<<N_SCAN_BLOCKS, SCAN_BLK, 0, stream>>>(cnt, partial, rowptr, dinv);
    scatter_kernel<<<N_EDGES / 256, 256, 0, stream>>>(esrc, edst, rowptr, woff, csr_src);
    wt_kernel<<<1, 256, 0, stream>>>(W1, wt1);
    wt_kernel<<<1, 256, 0, stream>>>(W2, wt2);

    int gemm_blocks = (N_NODES + 63) / 64;
    int agg_blocks = (N_NODES + 15) / 16;
    // layer 1
    gemm_kernel<<<gemm_blocks, 256, 0, stream>>>(x, wt1, dinv, bufG, N_NODES);
    aggregate_kernel<<<agg_blocks, 256, 0, stream>>>((const uint4*)bufG, dinv, rowptr, csr_src, b1, bufH, N_NODES);
    // layer 2
    gemm_kernel<<<gemm_blocks, 256, 0, stream>>>(bufH, wt2, dinv, bufG, N_NODES);
    aggregate_kernel<<<agg_blocks, 256, 0, stream>>>((const uint4*)bufG, dinv, rowptr, csr_src, b2, bufH, N_NODES);
    // readout
    readout_kernel<<<N_GRAPHS, 256, 0, stream>>>(bufH, batch, out);
}